// Round 17
// baseline (104.799 us; speedup 1.0000x reference)
//
#include <hip/hip_runtime.h>
#include <cmath>

#define Bz 4
#define Tz 1000
#define Wz 32
#define Dz 200
#define EDz 400
#define Nz 16
#define DTRz 13
#define Lz 1001
#define POSz 500
#define LPz 501
#define TSTR 512
#define NEE 7        // e-tiles of 64 in k_gemmid
#define NZB 8        // zero-fill blocks in k_front
#define ZTOT 29728   // (53248+65536+128)/4 float4s to zero
#define NEG_BIG -1e30f

__device__ __forceinline__ float wave_sum(float v) {
#pragma unroll
  for (int o = 32; o; o >>= 1) v += __shfl_xor(v, o);
  return v;
}

// grid = 9 + 8 + 1000 blocks. 0..8: setup. 9..16: zero dfin/Bm/Cend.
// 17..: pool (1 wave/tweet).
__global__ __launch_bounds__(256) void k_front(
    const float* __restrict__ x, const int* __restrict__ n_tweets,
    const int* __restrict__ n_words, const float* __restrict__ w_attn,
    const float* __restrict__ b_attn, const float* __restrict__ norm_w,
    const float* __restrict__ cls, const float* __restrict__ out_proj,
    const float* __restrict__ head_w, const float* __restrict__ ipf,
    const float* __restrict__ ipb, float* __restrict__ xn,
    float* __restrict__ zbuf, float* __restrict__ vbuf,
    float* __restrict__ zero_base) {
  int bid = blockIdx.x;
  int tid = threadIdx.x;
  int wave = tid >> 6, lane = tid & 63;
  if (bid < 9) {
    if (bid == 0) {
      __shared__ float hw[Dz];
      if (tid < Dz) hw[tid] = head_w[tid];
      __syncthreads();
      for (int e = tid; e < EDz; e += 256) {
        float acc = 0.f;
        for (int d = 0; d < Dz; d += 4) {
          float4 ov = *(const float4*)(out_proj + e * Dz + d);
          acc += ov.x * hw[d] + ov.y * hw[d + 1] + ov.z * hw[d + 2] + ov.w * hw[d + 3];
        }
        vbuf[e] = acc;
      }
      return;
    }
    int id = bid - 1;
    int br = id >> 2, b = id & 3;
    __shared__ float xs[Dz];
    __shared__ float s_red[4];
    float val = (tid < Dz) ? cls[tid] : 0.f;
    float sq = wave_sum(val * val);
    if ((tid & 63) == 0) s_red[tid >> 6] = sq;
    __syncthreads();
    float tot = s_red[0] + s_red[1] + s_red[2] + s_red[3];
    float scale = rsqrtf(tot * (1.f / Dz) + 1e-5f);
    if (tid < Dz) {
      float o = val * scale * norm_w[tid];
      xs[tid] = o;
      if (br == 0) xn[((size_t)b * Lz + POSz) * Dz + tid] = o;
    }
    __syncthreads();
    const float* ip = br ? ipb : ipf;
    for (int e = tid; e < EDz; e += 256) {
      float acc = 0.f;
      for (int d = 0; d < Dz; ++d) acc += xs[d] * ip[d * (2 * EDz) + EDz + e];
      zbuf[((size_t)br * Bz + b) * EDz + e] = acc;
    }
    return;
  }
  if (bid < 9 + NZB) {
    int zb = bid - 9;
    float4* z = (float4*)zero_base;
    int per = ZTOT / NZB;   // 3716
    for (int i = tid; i < per; i += 256)
      z[zb * per + i] = make_float4(0.f, 0.f, 0.f, 0.f);
    return;
  }
  int bt = (bid - 9 - NZB) * 4 + wave;
  int b = bt / Tz, t = bt - b * Tz;
  int l = (t < POSz) ? t : t + 1;
  float* outr = xn + ((size_t)b * Lz + l) * Dz;
  int ntw = n_tweets[b]; if (ntw > Tz) ntw = Tz;
  if (t >= ntw) {
    if (lane < 50) *(float4*)(outr + lane * 4) = make_float4(0.f, 0.f, 0.f, 0.f);
    return;
  }
  int nw = n_words[b * Tz + t]; if (nw > Wz) nw = Wz; if (nw < 1) nw = 1;
  const float* xs = x + ((size_t)(b * Tz + t)) * (Wz * Dz);
  int h = lane & 1, w = lane >> 1;
  float sc = 0.f;
  if (w < nw) {
    const float* xr = xs + w * Dz + h * 100;
    const float* wr = w_attn + h * 100;
#pragma unroll
    for (int i = 0; i < 25; ++i) {
      float4 xv = *(const float4*)(xr + i * 4);
      float4 wv = *(const float4*)(wr + i * 4);
      sc += xv.x * wv.x + xv.y * wv.y + xv.z * wv.z + xv.w * wv.w;
    }
  }
  sc += __shfl_xor(sc, 1);
  float scv = (w < nw) ? (sc + b_attn[0]) : NEG_BIG;
  float m = scv;
#pragma unroll
  for (int o = 32; o; o >>= 1) m = fmaxf(m, __shfl_xor(m, o));
  float en = __expf(scv - m);
  float es = (h == 0) ? en : 0.f;
  float tot = wave_sum(es);
  en /= tot;
  float4 val = make_float4(0.f, 0.f, 0.f, 0.f);
  const float* xc = xs + lane * 4;
  for (int ww = 0; ww < nw; ++ww) {
    float aw = __shfl(en, 2 * ww);
    if (lane < 50) {
      float4 xv = *(const float4*)(xc + ww * Dz);
      val.x += aw * xv.x; val.y += aw * xv.y;
      val.z += aw * xv.z; val.w += aw * xv.w;
    }
  }
  float sq = (lane < 50) ? (val.x * val.x + val.y * val.y + val.z * val.z + val.w * val.w) : 0.f;
  sq = wave_sum(sq);
  float scale = rsqrtf(sq * (1.f / Dz) + 1e-5f);
  if (lane < 50) {
    float4 nw4 = *(const float4*)(norm_w + lane * 4);
    float4 o = make_float4(val.x * scale * nw4.x, val.y * scale * nw4.y,
                           val.z * scale * nw4.z, val.w * scale * nw4.w);
    *(float4*)(outr + lane * 4) = o;
  }
}

// Fused in_proj GEMM + conv/silu + xproj. Phase-2 re-mapped: wave owns 16 t's,
// 4-lane subgroups split e -> shuffle reduce, NO sred buffer, no extra
// barriers. LDS ~35 KB -> 4 blocks/CU.
// grid = brb(8) x tt(8) x ee(7) = 448 blocks, 256 threads.
__global__ __launch_bounds__(256) void k_gemmid(
    const float* __restrict__ xn,
    const float* __restrict__ ipf, const float* __restrict__ ipb,
    const float* __restrict__ cwf, const float* __restrict__ cwb,
    const float* __restrict__ cbf, const float* __restrict__ cbb,
    const float* __restrict__ xpjf, const float* __restrict__ xpjb,
    float* __restrict__ xp_t, float* __restrict__ dfin_g,
    float* __restrict__ Bm_t, float* __restrict__ Cend) {
  int bid = blockIdx.x;
  int ee = bid % NEE;
  int rem = bid / NEE;
  int tt = rem & 7, brb = rem >> 3;
  int br = brb >> 2, b = brb & 3;
  int t0 = tt * 64, e0 = ee * 64;
  int tid = threadIdx.x;
  int wave = tid >> 6, lane = tid & 63;
  const float* ip = br ? ipb : ipf;
  const float* cw = br ? cwb : cwf;
  const float* cb = br ? cbb : cbf;
  const float* xpj = br ? xpjb : xpjf;

  __shared__ float Xs[16][132];      // [d][16 groups * 8 + pad]  8.4 KB
  __shared__ float Ws[16][68];       // [d][e(64)+pad]            4.3 KB
  __shared__ float Pl[80][69];       // [trow][e]                22.1 KB

  int tx = tid & 15, ty = tid >> 4;

  const float* xr_[5];
  bool vr_[5];
  int colr_[5];
#pragma unroll
  for (int r = 0; r < 5; ++r) {
    int trow = r * 16 + ty;
    int t = t0 - 8 + trow;
    bool ok = (t >= 0 && t < LPz);
    int tc2 = ok ? t : 0;
    int l = br ? (Lz - 1 - tc2) : tc2;
    xr_[r] = xn + ((size_t)b * Lz + l) * Dz;
    vr_[r] = ok;
    colr_[r] = (trow / 5) * 8 + (trow % 5);
  }

  float acc[5][4];
#pragma unroll
  for (int i = 0; i < 5; ++i)
#pragma unroll
    for (int j = 0; j < 4; ++j) acc[i][j] = 0.f;

  float xv[5], wv[4];
#pragma unroll
  for (int r = 0; r < 5; ++r) xv[r] = vr_[r] ? xr_[r][tx] : 0.f;
#pragma unroll
  for (int c = 0; c < 4; ++c)
    wv[c] = ip[(size_t)ty * (2 * EDz) + e0 + tx * 4 + c];

  for (int it = 0; it < 13; ++it) {
    __syncthreads();
#pragma unroll
    for (int r = 0; r < 5; ++r) Xs[tx][colr_[r]] = xv[r];
#pragma unroll
    for (int c = 0; c < 4; ++c) Ws[ty][tx * 4 + c] = wv[c];
    __syncthreads();
    if (it < 12) {
      int dk = (it + 1) * 16;
      int d = dk + tx;
      bool dok = (d < Dz);
#pragma unroll
      for (int r = 0; r < 5; ++r)
        xv[r] = (vr_[r] && dok) ? xr_[r][d] : 0.f;
      int dw = dk + ty;
      bool wok = (dw < Dz);
#pragma unroll
      for (int c = 0; c < 4; ++c)
        wv[c] = wok ? ip[(size_t)dw * (2 * EDz) + e0 + tx * 4 + c] : 0.f;
    }
#pragma unroll
    for (int k = 0; k < 16; ++k) {
      float4 a4 = *(const float4*)&Xs[k][ty * 8];
      float a5 = Xs[k][ty * 8 + 4];
      float4 b4 = *(const float4*)&Ws[k][tx * 4];
      float av[5] = {a4.x, a4.y, a4.z, a4.w, a5};
      float bv[4] = {b4.x, b4.y, b4.z, b4.w};
#pragma unroll
      for (int i = 0; i < 5; ++i)
#pragma unroll
        for (int j = 0; j < 4; ++j) acc[i][j] += av[i] * bv[j];
    }
  }
  __syncthreads();
#pragma unroll
  for (int i = 0; i < 5; ++i)
#pragma unroll
    for (int j = 0; j < 4; ++j) Pl[ty * 5 + i][tx * 4 + j] = acc[i][j];
  __syncthreads();

  // phase 2: conv+silu -> xp_t ; xproj. wave owns 16 t's (tl), es = e-quarter.
  int tl = lane >> 2, es = lane & 3;
  int t = t0 + wave * 16 + tl;
  int row = wave * 16 + tl + 8;
  float accq[45];
#pragma unroll
  for (int q = 0; q < 45; ++q) accq[q] = 0.f;
#pragma unroll 2
  for (int i = 0; i < 16; ++i) {
    int e_loc = es * 16 + i;
    int e = e0 + e_loc;
    if (e < EDz) {
      float p0 = Pl[row - 3][e_loc];
      float p1 = Pl[row - 2][e_loc];
      float p2 = Pl[row - 1][e_loc];
      float p3 = Pl[row][e_loc];
      float4 c4 = *(const float4*)(cw + e * 4);
      float a = cb[e] + c4.x * p0 + c4.y * p1 + c4.z * p2 + c4.w * p3;
      float sp = a / (1.f + __expf(-a));
      xp_t[((size_t)brb * EDz + e) * TSTR + t] = sp;
      const float* xq = xpj + e * 45;
#pragma unroll
      for (int q = 0; q < 45; ++q) accq[q] += sp * xq[q];
    }
  }
  // 4-lane shuffle reduce over the e-quarters
#pragma unroll
  for (int q = 0; q < 45; ++q) {
    accq[q] += __shfl_xor(accq[q], 1);
    accq[q] += __shfl_xor(accq[q], 2);
  }
  if (es == 0) {
#pragma unroll
    for (int q = 0; q < DTRz; ++q)
      atomicAdd(&dfin_g[((size_t)brb * DTRz + q) * TSTR + t], accq[q]);
#pragma unroll
    for (int n = 0; n < Nz; ++n)
      atomicAdd(&Bm_t[((size_t)brb * Nz + n) * TSTR + t], accq[13 + n]);
    if (t == POSz) {
#pragma unroll
      for (int n = 0; n < Nz; ++n)
        atomicAdd(&Cend[brb * Nz + n], accq[29 + n]);
    }
  }
}

// Scan, 8 e's per block (8 waves): dfin+Bm staged ONCE to LDS per block.
// grid = brb(8) x eg(50) = 400 blocks, 512 threads.
__global__ __launch_bounds__(512) void k_scan3(
    const float* __restrict__ xp_t, const float* __restrict__ dfin_g,
    const float* __restrict__ Bm_t, const float* __restrict__ Cend,
    const float* __restrict__ Alogf, const float* __restrict__ Alogb,
    const float* __restrict__ Dpf, const float* __restrict__ Dpb,
    const float* __restrict__ dtwf, const float* __restrict__ dtwb,
    const float* __restrict__ dtbf, const float* __restrict__ dtbb,
    const float* __restrict__ zbuf, const float* __restrict__ vbuf,
    float* __restrict__ ybuf) {
  int bid = blockIdx.x;
  int eg = bid % 50, brb = bid / 50;
  int br = brb >> 2;
  int tid = threadIdx.x;
  int wave = tid >> 6, lane = tid & 63;
  int e = eg * 8 + wave;

  __shared__ float sdf[DTRz * TSTR];   // 26624 B
  __shared__ float sbm[Nz * TSTR];     // 32768 B

  {
    const float4* src = (const float4*)(dfin_g + (size_t)brb * DTRz * TSTR);
    float4* dst = (float4*)sdf;
    for (int i = tid; i < DTRz * TSTR / 4; i += 512) dst[i] = src[i];
    const float4* src2 = (const float4*)(Bm_t + (size_t)brb * Nz * TSTR);
    float4* dst2 = (float4*)sbm;
    for (int i = tid; i < Nz * TSTR / 4; i += 512) dst2[i] = src2[i];
  }
  __syncthreads();

  const float* A_log = br ? Alogb : Alogf;
  const float* Dp = br ? Dpb : Dpf;
  const float* dtw = br ? dtwb : dtwf;
  const float* dtb = br ? dtbb : dtbf;
  float A[Nz];
  {
    const float4* ap = (const float4*)(A_log + e * Nz);
#pragma unroll
    for (int q = 0; q < 4; ++q) {
      float4 a4 = ap[q];
      A[q * 4 + 0] = -__expf(a4.x); A[q * 4 + 1] = -__expf(a4.y);
      A[q * 4 + 2] = -__expf(a4.z); A[q * 4 + 3] = -__expf(a4.w);
    }
  }
  float wq[DTRz];
#pragma unroll
  for (int q = 0; q < DTRz; ++q) wq[q] = dtw[q * EDz + e];
  float dtbe = dtb[e];
  const float* xpp = xp_t + ((size_t)brb * EDz + e) * TSTR;

  float dtt_r[8];
  float loc = 0.f;
#pragma unroll
  for (int c = 0; c < 8; ++c) {
    int t = c * 64 + lane;
    float s = dtbe;
#pragma unroll
    for (int q = 0; q < DTRz; ++q) s += sdf[q * TSTR + t] * wq[q];
    float dtv = (s > 20.f) ? s : log1pf(__expf(s));
    dtv = (t < LPz) ? dtv : 0.f;
    dtt_r[c] = dtv;
    loc += dtv;
  }
  float Stot = wave_sum(loc);
  float acc[Nz];
#pragma unroll
  for (int n = 0; n < Nz; ++n) acc[n] = 0.f;
  float carry = 0.f;
  for (int c = 0; c < 8; ++c) {
    int t = c * 64 + lane;
    bool act = t < LPz;
    float dtt = dtt_r[c];
    float xv = act ? xpp[t] : 0.f;
    float s = dtt;
#pragma unroll
    for (int o = 1; o < 64; o <<= 1) {
      float u = __shfl_up(s, o);
      s += (lane >= o) ? u : 0.f;
    }
    float S = carry + s;
    carry += __shfl(s, 63);
    float wt = dtt * xv;
    float decay = Stot - S;  // >= 0, A<0 => exp<=1
#pragma unroll
    for (int n = 0; n < Nz; ++n) {
      float bv = act ? sbm[n * TSTR + t] : 0.f;
      acc[n] += __expf(A[n] * decay) * wt * bv;
    }
  }
#pragma unroll
  for (int o = 32; o; o >>= 1) {
#pragma unroll
    for (int n = 0; n < Nz; ++n) acc[n] += __shfl_xor(acc[n], o);
  }
  if (lane == 0) {
    float y = Dp[e] * xpp[LPz - 1];
#pragma unroll
    for (int n = 0; n < Nz; ++n) y += Cend[brb * Nz + n] * acc[n];
    float zz = zbuf[(size_t)brb * EDz + e];
    float sz = zz / (1.f + __expf(-zz));
    ybuf[(size_t)brb * EDz + e] = y * sz * vbuf[e];
  }
}

__global__ __launch_bounds__(256) void k_final(
    const float* __restrict__ cls, const float* __restrict__ head_w,
    const float* __restrict__ head_b, const float* __restrict__ ybuf,
    float* __restrict__ out) {
  int tid = threadIdx.x;
  int b = tid >> 6, lane = tid & 63;
  float acc = 0.f;
  for (int e = lane; e < EDz; e += 64)
    acc += ybuf[(size_t)b * EDz + e] + ybuf[(size_t)(Bz + b) * EDz + e];
  for (int d = lane; d < Dz; d += 64) acc += cls[d] * head_w[d];
  acc = wave_sum(acc);
  if (lane == 0) out[b] = 1.f / (1.f + __expf(-(acc + head_b[0])));
}

extern "C" void kernel_launch(void* const* d_in, const int* in_sizes, int n_in,
                              void* d_out, int out_size, void* d_ws, size_t ws_size,
                              hipStream_t stream) {
  const float* input_ids = (const float*)d_in[0];
  const int* n_tweets = (const int*)d_in[1];
  const int* n_words = (const int*)d_in[2];
  const float* cls = (const float*)d_in[3];
  const float* w_attn = (const float*)d_in[4];
  const float* b_attn = (const float*)d_in[5];
  const float* norm_w = (const float*)d_in[6];
  const float* ip[2] = {(const float*)d_in[7], (const float*)d_in[15]};
  const float* cw[2] = {(const float*)d_in[8], (const float*)d_in[16]};
  const float* cb[2] = {(const float*)d_in[9], (const float*)d_in[17]};
  const float* xpj[2] = {(const float*)d_in[10], (const float*)d_in[18]};
  const float* dtw[2] = {(const float*)d_in[11], (const float*)d_in[19]};
  const float* dtbp[2] = {(const float*)d_in[12], (const float*)d_in[20]};
  const float* Alog[2] = {(const float*)d_in[13], (const float*)d_in[21]};
  const float* Dpp[2] = {(const float*)d_in[14], (const float*)d_in[22]};
  const float* out_proj = (const float*)d_in[23];
  const float* head_w = (const float*)d_in[24];
  const float* head_b = (const float*)d_in[25];
  float* out = (float*)d_out;

  float* ws = (float*)d_ws;
  float* xn = ws;                           // 800800
  float* xp_t = xn + 800800;                // 1638400
  float* dfin = xp_t + 1638400;             // 53248   } contiguous zero range
  float* Bm_t = dfin + 53248;               // 65536   }
  float* Cend = Bm_t + 65536;               // 128     } (118912)
  float* zbuf = Cend + 128;                 // 3200
  float* vbuf = zbuf + 3200;                // 400
  float* ybuf = vbuf + 400;                 // 3200

  hipLaunchKernelGGL(k_front, dim3(9 + NZB + Bz * Tz / 4), dim3(256), 0, stream,
                     input_ids, n_tweets, n_words, w_attn, b_attn, norm_w,
                     cls, out_proj, head_w, ip[0], ip[1], xn, zbuf, vbuf, dfin);
  hipLaunchKernelGGL(k_gemmid, dim3(2 * Bz * 8 * NEE), dim3(256), 0, stream,
                     xn, ip[0], ip[1], cw[0], cw[1], cb[0], cb[1],
                     xpj[0], xpj[1], xp_t, dfin, Bm_t, Cend);
  hipLaunchKernelGGL(k_scan3, dim3(2 * Bz * 50), dim3(512), 0, stream,
                     xp_t, dfin, Bm_t, Cend, Alog[0], Alog[1], Dpp[0], Dpp[1],
                     dtw[0], dtw[1], dtbp[0], dtbp[1], zbuf, vbuf, ybuf);
  hipLaunchKernelGGL(k_final, dim3(1), dim3(256), 0, stream,
                     cls, head_w, head_b, ybuf, out);
}

// Round 18
// 99.452 us; speedup vs baseline: 1.0538x; 1.0538x over previous
//
#include <hip/hip_runtime.h>
#include <cmath>

#define Bz 4
#define Tz 1000
#define Wz 32
#define Dz 200
#define EDz 400
#define Nz 16
#define DTRz 13
#define Lz 1001
#define POSz 500
#define LPz 501
#define TSTR 512
#define NEE 7        // e-tiles of 64 in k_gemmid
#define NZB 8        // zero-fill blocks in k_front
#define ZTOT 29728   // (53248+65536+128)/4 float4s to zero
#define NEG_BIG -1e30f

__device__ __forceinline__ float wave_sum(float v) {
#pragma unroll
  for (int o = 32; o; o >>= 1) v += __shfl_xor(v, o);
  return v;
}

// grid = 9 + 8 + 1000 blocks. 0..8: setup. 9..16: zero dfin/Bm/Cend.
// 17..: pool (1 wave/tweet).
__global__ __launch_bounds__(256) void k_front(
    const float* __restrict__ x, const int* __restrict__ n_tweets,
    const int* __restrict__ n_words, const float* __restrict__ w_attn,
    const float* __restrict__ b_attn, const float* __restrict__ norm_w,
    const float* __restrict__ cls, const float* __restrict__ out_proj,
    const float* __restrict__ head_w, const float* __restrict__ ipf,
    const float* __restrict__ ipb, float* __restrict__ xn,
    float* __restrict__ zbuf, float* __restrict__ vbuf,
    float* __restrict__ zero_base) {
  int bid = blockIdx.x;
  int tid = threadIdx.x;
  int wave = tid >> 6, lane = tid & 63;
  if (bid < 9) {
    if (bid == 0) {
      __shared__ float hw[Dz];
      if (tid < Dz) hw[tid] = head_w[tid];
      __syncthreads();
      for (int e = tid; e < EDz; e += 256) {
        float acc = 0.f;
        for (int d = 0; d < Dz; d += 4) {
          float4 ov = *(const float4*)(out_proj + e * Dz + d);
          acc += ov.x * hw[d] + ov.y * hw[d + 1] + ov.z * hw[d + 2] + ov.w * hw[d + 3];
        }
        vbuf[e] = acc;
      }
      return;
    }
    int id = bid - 1;
    int br = id >> 2, b = id & 3;
    __shared__ float xs[Dz];
    __shared__ float s_red[4];
    float val = (tid < Dz) ? cls[tid] : 0.f;
    float sq = wave_sum(val * val);
    if ((tid & 63) == 0) s_red[tid >> 6] = sq;
    __syncthreads();
    float tot = s_red[0] + s_red[1] + s_red[2] + s_red[3];
    float scale = rsqrtf(tot * (1.f / Dz) + 1e-5f);
    if (tid < Dz) {
      float o = val * scale * norm_w[tid];
      xs[tid] = o;
      if (br == 0) xn[((size_t)b * Lz + POSz) * Dz + tid] = o;
    }
    __syncthreads();
    const float* ip = br ? ipb : ipf;
    for (int e = tid; e < EDz; e += 256) {
      float acc = 0.f;
      for (int d = 0; d < Dz; ++d) acc += xs[d] * ip[d * (2 * EDz) + EDz + e];
      zbuf[((size_t)br * Bz + b) * EDz + e] = acc;
    }
    return;
  }
  if (bid < 9 + NZB) {
    int zb = bid - 9;
    float4* z = (float4*)zero_base;
    int per = ZTOT / NZB;   // 3716
    for (int i = tid; i < per; i += 256)
      z[zb * per + i] = make_float4(0.f, 0.f, 0.f, 0.f);
    return;
  }
  int bt = (bid - 9 - NZB) * 4 + wave;
  int b = bt / Tz, t = bt - b * Tz;
  int l = (t < POSz) ? t : t + 1;
  float* outr = xn + ((size_t)b * Lz + l) * Dz;
  int ntw = n_tweets[b]; if (ntw > Tz) ntw = Tz;
  if (t >= ntw) {
    if (lane < 50) *(float4*)(outr + lane * 4) = make_float4(0.f, 0.f, 0.f, 0.f);
    return;
  }
  int nw = n_words[b * Tz + t]; if (nw > Wz) nw = Wz; if (nw < 1) nw = 1;
  const float* xs = x + ((size_t)(b * Tz + t)) * (Wz * Dz);
  int h = lane & 1, w = lane >> 1;
  float sc = 0.f;
  if (w < nw) {
    const float* xr = xs + w * Dz + h * 100;
    const float* wr = w_attn + h * 100;
#pragma unroll
    for (int i = 0; i < 25; ++i) {
      float4 xv = *(const float4*)(xr + i * 4);
      float4 wv = *(const float4*)(wr + i * 4);
      sc += xv.x * wv.x + xv.y * wv.y + xv.z * wv.z + xv.w * wv.w;
    }
  }
  sc += __shfl_xor(sc, 1);
  float scv = (w < nw) ? (sc + b_attn[0]) : NEG_BIG;
  float m = scv;
#pragma unroll
  for (int o = 32; o; o >>= 1) m = fmaxf(m, __shfl_xor(m, o));
  float en = __expf(scv - m);
  float es = (h == 0) ? en : 0.f;
  float tot = wave_sum(es);
  en /= tot;
  float4 val = make_float4(0.f, 0.f, 0.f, 0.f);
  const float* xc = xs + lane * 4;
  for (int ww = 0; ww < nw; ++ww) {
    float aw = __shfl(en, 2 * ww);
    if (lane < 50) {
      float4 xv = *(const float4*)(xc + ww * Dz);
      val.x += aw * xv.x; val.y += aw * xv.y;
      val.z += aw * xv.z; val.w += aw * xv.w;
    }
  }
  float sq = (lane < 50) ? (val.x * val.x + val.y * val.y + val.z * val.z + val.w * val.w) : 0.f;
  sq = wave_sum(sq);
  float scale = rsqrtf(sq * (1.f / Dz) + 1e-5f);
  if (lane < 50) {
    float4 nw4 = *(const float4*)(norm_w + lane * 4);
    float4 o = make_float4(val.x * scale * nw4.x, val.y * scale * nw4.y,
                           val.z * scale * nw4.z, val.w * scale * nw4.w);
    *(float4*)(outr + lane * 4) = o;
  }
}

// Fused in_proj GEMM (80t x 64e) with DOUBLE-BUFFERED LDS staging (1 barrier
// per K-step instead of 2) + register prefetch -> conv+silu -> xp_t ; xproj
// partials (R14 parallel sred) -> atomics.
// grid = brb(8) x tt(8) x ee(7) = 448 blocks, 256 threads.
__global__ __launch_bounds__(256) void k_gemmid(
    const float* __restrict__ xn,
    const float* __restrict__ ipf, const float* __restrict__ ipb,
    const float* __restrict__ cwf, const float* __restrict__ cwb,
    const float* __restrict__ cbf, const float* __restrict__ cbb,
    const float* __restrict__ xpjf, const float* __restrict__ xpjb,
    float* __restrict__ xp_t, float* __restrict__ dfin_g,
    float* __restrict__ Bm_t, float* __restrict__ Cend) {
  int bid = blockIdx.x;
  int ee = bid % NEE;
  int rem = bid / NEE;
  int tt = rem & 7, brb = rem >> 3;
  int br = brb >> 2, b = brb & 3;
  int t0 = tt * 64, e0 = ee * 64;
  int tid = threadIdx.x;
  int wave = tid >> 6, lane = tid & 63;
  const float* ip = br ? ipb : ipf;
  const float* cw = br ? cwb : cwf;
  const float* cb = br ? cbb : cbf;
  const float* xpj = br ? xpjb : xpjf;

  __shared__ float Xs[2][16][132];   // double-buffered [d][16 groups*8+pad]
  __shared__ float Ws[2][16][68];
  __shared__ float Pl[80][69];       // [trow][e]
  __shared__ float sred[4][64][45];

  int tx = tid & 15, ty = tid >> 4;  // tx: e-micro / d-stage; ty: t-group

  const float* xr_[5];
  bool vr_[5];
  int colr_[5];
#pragma unroll
  for (int r = 0; r < 5; ++r) {
    int trow = r * 16 + ty;
    int t = t0 - 8 + trow;
    bool ok = (t >= 0 && t < LPz);
    int tc2 = ok ? t : 0;
    int l = br ? (Lz - 1 - tc2) : tc2;
    xr_[r] = xn + ((size_t)b * Lz + l) * Dz;
    vr_[r] = ok;
    colr_[r] = (trow / 5) * 8 + (trow % 5);
  }

  float acc[5][4];
#pragma unroll
  for (int i = 0; i < 5; ++i)
#pragma unroll
    for (int j = 0; j < 4; ++j) acc[i][j] = 0.f;

  float xv[5];
  float4 w4;
  // prologue: loads for dk=0 -> regs -> buf0
#pragma unroll
  for (int r = 0; r < 5; ++r) xv[r] = vr_[r] ? xr_[r][tx] : 0.f;
  w4 = *(const float4*)(ip + (size_t)ty * (2 * EDz) + e0 + tx * 4);
#pragma unroll
  for (int r = 0; r < 5; ++r) Xs[0][tx][colr_[r]] = xv[r];
  *(float4*)&Ws[0][ty][tx * 4] = w4;
  __syncthreads();

  for (int it = 0; it < 13; ++it) {
    int cur = it & 1;
    if (it < 12) {
      int dk = (it + 1) * 16;
      int d = dk + tx;
      bool dok = (d < Dz);
#pragma unroll
      for (int r = 0; r < 5; ++r)
        xv[r] = (vr_[r] && dok) ? xr_[r][d] : 0.f;
      int dw = dk + ty;
      bool wok = (dw < Dz);
      int dwc = wok ? dw : (Dz - 1);
      w4 = *(const float4*)(ip + (size_t)dwc * (2 * EDz) + e0 + tx * 4);
      if (!wok) w4 = make_float4(0.f, 0.f, 0.f, 0.f);
    }
#pragma unroll
    for (int k = 0; k < 16; ++k) {
      float4 a4 = *(const float4*)&Xs[cur][k][ty * 8];
      float a5 = Xs[cur][k][ty * 8 + 4];
      float4 b4 = *(const float4*)&Ws[cur][k][tx * 4];
      float av[5] = {a4.x, a4.y, a4.z, a4.w, a5};
      float bv[4] = {b4.x, b4.y, b4.z, b4.w};
#pragma unroll
      for (int i = 0; i < 5; ++i)
#pragma unroll
        for (int j = 0; j < 4; ++j) acc[i][j] += av[i] * bv[j];
    }
    if (it < 12) {
      int nxt = cur ^ 1;
#pragma unroll
      for (int r = 0; r < 5; ++r) Xs[nxt][tx][colr_[r]] = xv[r];
      *(float4*)&Ws[nxt][ty][tx * 4] = w4;
      __syncthreads();
    }
  }
  __syncthreads();
#pragma unroll
  for (int i = 0; i < 5; ++i)
#pragma unroll
    for (int j = 0; j < 4; ++j) Pl[ty * 5 + i][tx * 4 + j] = acc[i][j];
  __syncthreads();

  // conv + silu + xproj partials. wave w owns 16 e's; lane = t. (R14 exact)
  float accq[45];
#pragma unroll
  for (int q = 0; q < 45; ++q) accq[q] = 0.f;
  int t = t0 + lane;
#pragma unroll 2
  for (int i = 0; i < 16; ++i) {
    int e_loc = wave * 16 + i;
    int e = e0 + e_loc;
    if (e < EDz) {
      int row = lane + 8;
      float p0 = Pl[row - 3][e_loc];
      float p1 = Pl[row - 2][e_loc];
      float p2 = Pl[row - 1][e_loc];
      float p3 = Pl[row][e_loc];
      float4 c4 = *(const float4*)(cw + e * 4);
      float a = cb[e] + c4.x * p0 + c4.y * p1 + c4.z * p2 + c4.w * p3;
      float sp = a / (1.f + __expf(-a));
      xp_t[((size_t)brb * EDz + e) * TSTR + t] = sp;
      const float* xq = xpj + e * 45;
#pragma unroll
      for (int q = 0; q < 45; ++q) accq[q] += sp * xq[q];
    }
  }
#pragma unroll
  for (int q = 0; q < 45; ++q) sred[wave][lane][q] = accq[q];
  __syncthreads();
  if (wave < 2) {
#pragma unroll
    for (int q = 0; q < 45; ++q)
      sred[wave][lane][q] += sred[wave + 2][lane][q];
  }
  __syncthreads();
  if (wave == 0) {
#pragma unroll
    for (int q = 0; q < DTRz; ++q) {
      float v = sred[0][lane][q] + sred[1][lane][q];
      atomicAdd(&dfin_g[((size_t)brb * DTRz + q) * TSTR + t], v);
    }
#pragma unroll
    for (int n = 0; n < Nz; ++n) {
      float v = sred[0][lane][13 + n] + sred[1][lane][13 + n];
      atomicAdd(&Bm_t[((size_t)brb * Nz + n) * TSTR + t], v);
    }
    if (tt == 7 && lane == (POSz - 448)) {
#pragma unroll
      for (int n = 0; n < Nz; ++n) {
        float v = sred[0][lane][29 + n] + sred[1][lane][29 + n];
        atomicAdd(&Cend[brb * Nz + n], v);
      }
    }
  }
}

// Scan, 8 e's per block (8 waves): dfin+Bm staged ONCE to LDS per block.
// grid = brb(8) x eg(50) = 400 blocks, 512 threads. (R14 exact)
__global__ __launch_bounds__(512) void k_scan3(
    const float* __restrict__ xp_t, const float* __restrict__ dfin_g,
    const float* __restrict__ Bm_t, const float* __restrict__ Cend,
    const float* __restrict__ Alogf, const float* __restrict__ Alogb,
    const float* __restrict__ Dpf, const float* __restrict__ Dpb,
    const float* __restrict__ dtwf, const float* __restrict__ dtwb,
    const float* __restrict__ dtbf, const float* __restrict__ dtbb,
    const float* __restrict__ zbuf, const float* __restrict__ vbuf,
    float* __restrict__ ybuf) {
  int bid = blockIdx.x;
  int eg = bid % 50, brb = bid / 50;
  int br = brb >> 2;
  int tid = threadIdx.x;
  int wave = tid >> 6, lane = tid & 63;
  int e = eg * 8 + wave;

  __shared__ float sdf[DTRz * TSTR];   // 26624 B
  __shared__ float sbm[Nz * TSTR];     // 32768 B

  {
    const float4* src = (const float4*)(dfin_g + (size_t)brb * DTRz * TSTR);
    float4* dst = (float4*)sdf;
    for (int i = tid; i < DTRz * TSTR / 4; i += 512) dst[i] = src[i];
    const float4* src2 = (const float4*)(Bm_t + (size_t)brb * Nz * TSTR);
    float4* dst2 = (float4*)sbm;
    for (int i = tid; i < Nz * TSTR / 4; i += 512) dst2[i] = src2[i];
  }
  __syncthreads();

  const float* A_log = br ? Alogb : Alogf;
  const float* Dp = br ? Dpb : Dpf;
  const float* dtw = br ? dtwb : dtwf;
  const float* dtb = br ? dtbb : dtbf;
  float A[Nz];
  {
    const float4* ap = (const float4*)(A_log + e * Nz);
#pragma unroll
    for (int q = 0; q < 4; ++q) {
      float4 a4 = ap[q];
      A[q * 4 + 0] = -__expf(a4.x); A[q * 4 + 1] = -__expf(a4.y);
      A[q * 4 + 2] = -__expf(a4.z); A[q * 4 + 3] = -__expf(a4.w);
    }
  }
  float wq[DTRz];
#pragma unroll
  for (int q = 0; q < DTRz; ++q) wq[q] = dtw[q * EDz + e];
  float dtbe = dtb[e];
  const float* xpp = xp_t + ((size_t)brb * EDz + e) * TSTR;

  float dtt_r[8];
  float loc = 0.f;
#pragma unroll
  for (int c = 0; c < 8; ++c) {
    int t = c * 64 + lane;
    float s = dtbe;
#pragma unroll
    for (int q = 0; q < DTRz; ++q) s += sdf[q * TSTR + t] * wq[q];
    float dtv = (s > 20.f) ? s : log1pf(__expf(s));
    dtv = (t < LPz) ? dtv : 0.f;
    dtt_r[c] = dtv;
    loc += dtv;
  }
  float Stot = wave_sum(loc);
  float acc[Nz];
#pragma unroll
  for (int n = 0; n < Nz; ++n) acc[n] = 0.f;
  float carry = 0.f;
  for (int c = 0; c < 8; ++c) {
    int t = c * 64 + lane;
    bool act = t < LPz;
    float dtt = dtt_r[c];
    float xv = act ? xpp[t] : 0.f;
    float s = dtt;
#pragma unroll
    for (int o = 1; o < 64; o <<= 1) {
      float u = __shfl_up(s, o);
      s += (lane >= o) ? u : 0.f;
    }
    float S = carry + s;
    carry += __shfl(s, 63);
    float wt = dtt * xv;
    float decay = Stot - S;  // >= 0, A<0 => exp<=1
#pragma unroll
    for (int n = 0; n < Nz; ++n) {
      float bv = act ? sbm[n * TSTR + t] : 0.f;
      acc[n] += __expf(A[n] * decay) * wt * bv;
    }
  }
#pragma unroll
  for (int o = 32; o; o >>= 1) {
#pragma unroll
    for (int n = 0; n < Nz; ++n) acc[n] += __shfl_xor(acc[n], o);
  }
  if (lane == 0) {
    float y = Dp[e] * xpp[LPz - 1];
#pragma unroll
    for (int n = 0; n < Nz; ++n) y += Cend[brb * Nz + n] * acc[n];
    float zz = zbuf[(size_t)brb * EDz + e];
    float sz = zz / (1.f + __expf(-zz));
    ybuf[(size_t)brb * EDz + e] = y * sz * vbuf[e];
  }
}

__global__ __launch_bounds__(256) void k_final(
    const float* __restrict__ cls, const float* __restrict__ head_w,
    const float* __restrict__ head_b, const float* __restrict__ ybuf,
    float* __restrict__ out) {
  int tid = threadIdx.x;
  int b = tid >> 6, lane = tid & 63;
  float acc = 0.f;
  for (int e = lane; e < EDz; e += 64)
    acc += ybuf[(size_t)b * EDz + e] + ybuf[(size_t)(Bz + b) * EDz + e];
  for (int d = lane; d < Dz; d += 64) acc += cls[d] * head_w[d];
  acc = wave_sum(acc);
  if (lane == 0) out[b] = 1.f / (1.f + __expf(-(acc + head_b[0])));
}

extern "C" void kernel_launch(void* const* d_in, const int* in_sizes, int n_in,
                              void* d_out, int out_size, void* d_ws, size_t ws_size,
                              hipStream_t stream) {
  const float* input_ids = (const float*)d_in[0];
  const int* n_tweets = (const int*)d_in[1];
  const int* n_words = (const int*)d_in[2];
  const float* cls = (const float*)d_in[3];
  const float* w_attn = (const float*)d_in[4];
  const float* b_attn = (const float*)d_in[5];
  const float* norm_w = (const float*)d_in[6];
  const float* ip[2] = {(const float*)d_in[7], (const float*)d_in[15]};
  const float* cw[2] = {(const float*)d_in[8], (const float*)d_in[16]};
  const float* cb[2] = {(const float*)d_in[9], (const float*)d_in[17]};
  const float* xpj[2] = {(const float*)d_in[10], (const float*)d_in[18]};
  const float* dtw[2] = {(const float*)d_in[11], (const float*)d_in[19]};
  const float* dtbp[2] = {(const float*)d_in[12], (const float*)d_in[20]};
  const float* Alog[2] = {(const float*)d_in[13], (const float*)d_in[21]};
  const float* Dpp[2] = {(const float*)d_in[14], (const float*)d_in[22]};
  const float* out_proj = (const float*)d_in[23];
  const float* head_w = (const float*)d_in[24];
  const float* head_b = (const float*)d_in[25];
  float* out = (float*)d_out;

  float* ws = (float*)d_ws;
  float* xn = ws;                           // 800800
  float* xp_t = xn + 800800;                // 1638400
  float* dfin = xp_t + 1638400;             // 53248   } contiguous zero range
  float* Bm_t = dfin + 53248;               // 65536   }
  float* Cend = Bm_t + 65536;               // 128     } (118912)
  float* zbuf = Cend + 128;                 // 3200
  float* vbuf = zbuf + 3200;                // 400
  float* ybuf = vbuf + 400;                 // 3200

  hipLaunchKernelGGL(k_front, dim3(9 + NZB + Bz * Tz / 4), dim3(256), 0, stream,
                     input_ids, n_tweets, n_words, w_attn, b_attn, norm_w,
                     cls, out_proj, head_w, ip[0], ip[1], xn, zbuf, vbuf, dfin);
  hipLaunchKernelGGL(k_gemmid, dim3(2 * Bz * 8 * NEE), dim3(256), 0, stream,
                     xn, ip[0], ip[1], cw[0], cw[1], cb[0], cb[1],
                     xpj[0], xpj[1], xp_t, dfin, Bm_t, Cend);
  hipLaunchKernelGGL(k_scan3, dim3(2 * Bz * 50), dim3(512), 0, stream,
                     xp_t, dfin, Bm_t, Cend, Alog[0], Alog[1], Dpp[0], Dpp[1],
                     dtw[0], dtw[1], dtbp[0], dtbp[1], zbuf, vbuf, ybuf);
  hipLaunchKernelGGL(k_final, dim3(1), dim3(256), 0, stream,
                     cls, head_w, head_b, ybuf, out);
}

// Round 19
// 86.957 us; speedup vs baseline: 1.2052x; 1.1437x over previous
//
#include <hip/hip_runtime.h>
#include <cmath>

#define Bz 4
#define Tz 1000
#define Wz 32
#define Dz 200
#define EDz 400
#define Nz 16
#define DTRz 13
#define Lz 1001
#define POSz 500
#define LPz 501
#define TSTR 512
#define NEE 7        // e-tiles of 64 in k_gemmid
#define NZB 8        // zero-fill blocks in k_front
#define ZTOT 29728   // (53248+65536+128)/4 float4s to zero
#define NEG_BIG -1e30f

__device__ __forceinline__ float wave_sum(float v) {
#pragma unroll
  for (int o = 32; o; o >>= 1) v += __shfl_xor(v, o);
  return v;
}

// grid = 9 + 8 + 1000 blocks. 0..8: setup. 9..16: zero dfin/Bm/Cend.
// 17..: pool (1 wave/tweet).
__global__ __launch_bounds__(256) void k_front(
    const float* __restrict__ x, const int* __restrict__ n_tweets,
    const int* __restrict__ n_words, const float* __restrict__ w_attn,
    const float* __restrict__ b_attn, const float* __restrict__ norm_w,
    const float* __restrict__ cls, const float* __restrict__ out_proj,
    const float* __restrict__ head_w, const float* __restrict__ ipf,
    const float* __restrict__ ipb, float* __restrict__ xn,
    float* __restrict__ zbuf, float* __restrict__ vbuf,
    float* __restrict__ zero_base) {
  int bid = blockIdx.x;
  int tid = threadIdx.x;
  int wave = tid >> 6, lane = tid & 63;
  if (bid < 9) {
    if (bid == 0) {
      __shared__ float hw[Dz];
      if (tid < Dz) hw[tid] = head_w[tid];
      __syncthreads();
      for (int e = tid; e < EDz; e += 256) {
        float acc = 0.f;
        for (int d = 0; d < Dz; d += 4) {
          float4 ov = *(const float4*)(out_proj + e * Dz + d);
          acc += ov.x * hw[d] + ov.y * hw[d + 1] + ov.z * hw[d + 2] + ov.w * hw[d + 3];
        }
        vbuf[e] = acc;
      }
      return;
    }
    int id = bid - 1;
    int br = id >> 2, b = id & 3;
    __shared__ float xs[Dz];
    __shared__ float s_red[4];
    float val = (tid < Dz) ? cls[tid] : 0.f;
    float sq = wave_sum(val * val);
    if ((tid & 63) == 0) s_red[tid >> 6] = sq;
    __syncthreads();
    float tot = s_red[0] + s_red[1] + s_red[2] + s_red[3];
    float scale = rsqrtf(tot * (1.f / Dz) + 1e-5f);
    if (tid < Dz) {
      float o = val * scale * norm_w[tid];
      xs[tid] = o;
      if (br == 0) xn[((size_t)b * Lz + POSz) * Dz + tid] = o;
    }
    __syncthreads();
    const float* ip = br ? ipb : ipf;
    for (int e = tid; e < EDz; e += 256) {
      float acc = 0.f;
      for (int d = 0; d < Dz; ++d) acc += xs[d] * ip[d * (2 * EDz) + EDz + e];
      zbuf[((size_t)br * Bz + b) * EDz + e] = acc;
    }
    return;
  }
  if (bid < 9 + NZB) {
    int zb = bid - 9;
    float4* z = (float4*)zero_base;
    int per = ZTOT / NZB;   // 3716
    for (int i = tid; i < per; i += 256)
      z[zb * per + i] = make_float4(0.f, 0.f, 0.f, 0.f);
    return;
  }
  int bt = (bid - 9 - NZB) * 4 + wave;
  int b = bt / Tz, t = bt - b * Tz;
  int l = (t < POSz) ? t : t + 1;
  float* outr = xn + ((size_t)b * Lz + l) * Dz;
  int ntw = n_tweets[b]; if (ntw > Tz) ntw = Tz;
  if (t >= ntw) {
    if (lane < 50) *(float4*)(outr + lane * 4) = make_float4(0.f, 0.f, 0.f, 0.f);
    return;
  }
  int nw = n_words[b * Tz + t]; if (nw > Wz) nw = Wz; if (nw < 1) nw = 1;
  const float* xs = x + ((size_t)(b * Tz + t)) * (Wz * Dz);
  int h = lane & 1, w = lane >> 1;
  float sc = 0.f;
  if (w < nw) {
    const float* xr = xs + w * Dz + h * 100;
    const float* wr = w_attn + h * 100;
#pragma unroll
    for (int i = 0; i < 25; ++i) {
      float4 xv = *(const float4*)(xr + i * 4);
      float4 wv = *(const float4*)(wr + i * 4);
      sc += xv.x * wv.x + xv.y * wv.y + xv.z * wv.z + xv.w * wv.w;
    }
  }
  sc += __shfl_xor(sc, 1);
  float scv = (w < nw) ? (sc + b_attn[0]) : NEG_BIG;
  float m = scv;
#pragma unroll
  for (int o = 32; o; o >>= 1) m = fmaxf(m, __shfl_xor(m, o));
  float en = __expf(scv - m);
  float es = (h == 0) ? en : 0.f;
  float tot = wave_sum(es);
  en /= tot;
  float4 val = make_float4(0.f, 0.f, 0.f, 0.f);
  const float* xc = xs + lane * 4;
  for (int ww = 0; ww < nw; ++ww) {
    float aw = __shfl(en, 2 * ww);
    if (lane < 50) {
      float4 xv = *(const float4*)(xc + ww * Dz);
      val.x += aw * xv.x; val.y += aw * xv.y;
      val.z += aw * xv.z; val.w += aw * xv.w;
    }
  }
  float sq = (lane < 50) ? (val.x * val.x + val.y * val.y + val.z * val.z + val.w * val.w) : 0.f;
  sq = wave_sum(sq);
  float scale = rsqrtf(sq * (1.f / Dz) + 1e-5f);
  if (lane < 50) {
    float4 nw4 = *(const float4*)(norm_w + lane * 4);
    float4 o = make_float4(val.x * scale * nw4.x, val.y * scale * nw4.y,
                           val.z * scale * nw4.z, val.w * scale * nw4.w);
    *(float4*)(outr + lane * 4) = o;
  }
}

// Fused in_proj GEMM (80t incl. halo x 64e) with register-prefetched staging
// and vectorized LDS reads -> conv+silu -> xp_t ; xproj partials -> atomics.
// grid = brb(8) x tt(8) x ee(7) = 448 blocks, 256 threads.
__global__ __launch_bounds__(256) void k_gemmid(
    const float* __restrict__ xn,
    const float* __restrict__ ipf, const float* __restrict__ ipb,
    const float* __restrict__ cwf, const float* __restrict__ cwb,
    const float* __restrict__ cbf, const float* __restrict__ cbb,
    const float* __restrict__ xpjf, const float* __restrict__ xpjb,
    float* __restrict__ xp_t, float* __restrict__ dfin_g,
    float* __restrict__ Bm_t, float* __restrict__ Cend) {
  int bid = blockIdx.x;
  int ee = bid % NEE;
  int rem = bid / NEE;
  int tt = rem & 7, brb = rem >> 3;
  int br = brb >> 2, b = brb & 3;
  int t0 = tt * 64, e0 = ee * 64;
  int tid = threadIdx.x;
  int wave = tid >> 6, lane = tid & 63;
  const float* ip = br ? ipb : ipf;
  const float* cw = br ? cwb : cwf;
  const float* cb = br ? cbb : cbf;
  const float* xpj = br ? xpjb : xpjf;

  __shared__ float Xs[16][132];      // [d][16 groups * 8 + pad]
  __shared__ float Ws[16][68];       // [d][e(64)+pad]
  __shared__ float Pl[80][69];       // [trow][e]
  __shared__ float sred[4][64][45];

  int tx = tid & 15, ty = tid >> 4;

  const float* xr_[5];
  bool vr_[5];
  int colr_[5];
#pragma unroll
  for (int r = 0; r < 5; ++r) {
    int trow = r * 16 + ty;
    int t = t0 - 8 + trow;
    bool ok = (t >= 0 && t < LPz);
    int tc2 = ok ? t : 0;
    int l = br ? (Lz - 1 - tc2) : tc2;
    xr_[r] = xn + ((size_t)b * Lz + l) * Dz;
    vr_[r] = ok;
    colr_[r] = (trow / 5) * 8 + (trow % 5);
  }

  float acc[5][4];
#pragma unroll
  for (int i = 0; i < 5; ++i)
#pragma unroll
    for (int j = 0; j < 4; ++j) acc[i][j] = 0.f;

  float xv[5], wv[4];
#pragma unroll
  for (int r = 0; r < 5; ++r) xv[r] = vr_[r] ? xr_[r][tx] : 0.f;
#pragma unroll
  for (int c = 0; c < 4; ++c)
    wv[c] = ip[(size_t)ty * (2 * EDz) + e0 + tx * 4 + c];

  for (int it = 0; it < 13; ++it) {
    __syncthreads();
#pragma unroll
    for (int r = 0; r < 5; ++r) Xs[tx][colr_[r]] = xv[r];
#pragma unroll
    for (int c = 0; c < 4; ++c) Ws[ty][tx * 4 + c] = wv[c];
    __syncthreads();
    if (it < 12) {
      int dk = (it + 1) * 16;
      int d = dk + tx;
      bool dok = (d < Dz);
#pragma unroll
      for (int r = 0; r < 5; ++r)
        xv[r] = (vr_[r] && dok) ? xr_[r][d] : 0.f;
      int dw = dk + ty;
      bool wok = (dw < Dz);
#pragma unroll
      for (int c = 0; c < 4; ++c)
        wv[c] = wok ? ip[(size_t)dw * (2 * EDz) + e0 + tx * 4 + c] : 0.f;
    }
#pragma unroll
    for (int k = 0; k < 16; ++k) {
      float4 a4 = *(const float4*)&Xs[k][ty * 8];
      float a5 = Xs[k][ty * 8 + 4];
      float4 b4 = *(const float4*)&Ws[k][tx * 4];
      float av[5] = {a4.x, a4.y, a4.z, a4.w, a5};
      float bv[4] = {b4.x, b4.y, b4.z, b4.w};
#pragma unroll
      for (int i = 0; i < 5; ++i)
#pragma unroll
        for (int j = 0; j < 4; ++j) acc[i][j] += av[i] * bv[j];
    }
  }
  __syncthreads();
#pragma unroll
  for (int i = 0; i < 5; ++i)
#pragma unroll
    for (int j = 0; j < 4; ++j) Pl[ty * 5 + i][tx * 4 + j] = acc[i][j];
  __syncthreads();

  float accq[45];
#pragma unroll
  for (int q = 0; q < 45; ++q) accq[q] = 0.f;
  int t = t0 + lane;
#pragma unroll 2
  for (int i = 0; i < 16; ++i) {
    int e_loc = wave * 16 + i;
    int e = e0 + e_loc;
    if (e < EDz) {
      int row = lane + 8;
      float p0 = Pl[row - 3][e_loc];
      float p1 = Pl[row - 2][e_loc];
      float p2 = Pl[row - 1][e_loc];
      float p3 = Pl[row][e_loc];
      float4 c4 = *(const float4*)(cw + e * 4);
      float a = cb[e] + c4.x * p0 + c4.y * p1 + c4.z * p2 + c4.w * p3;
      float sp = a / (1.f + __expf(-a));
      xp_t[((size_t)brb * EDz + e) * TSTR + t] = sp;
      const float* xq = xpj + e * 45;
#pragma unroll
      for (int q = 0; q < 45; ++q) accq[q] += sp * xq[q];
    }
  }
#pragma unroll
  for (int q = 0; q < 45; ++q) sred[wave][lane][q] = accq[q];
  __syncthreads();
  if (wave < 2) {
#pragma unroll
    for (int q = 0; q < 45; ++q)
      sred[wave][lane][q] += sred[wave + 2][lane][q];
  }
  __syncthreads();
  if (wave == 0) {
#pragma unroll
    for (int q = 0; q < DTRz; ++q) {
      float v = sred[0][lane][q] + sred[1][lane][q];
      atomicAdd(&dfin_g[((size_t)brb * DTRz + q) * TSTR + t], v);
    }
#pragma unroll
    for (int n = 0; n < Nz; ++n) {
      float v = sred[0][lane][13 + n] + sred[1][lane][13 + n];
      atomicAdd(&Bm_t[((size_t)brb * Nz + n) * TSTR + t], v);
    }
    if (tt == 7 && lane == (POSz - 448)) {
#pragma unroll
      for (int n = 0; n < Nz; ++n) {
        float v = sred[0][lane][29 + n] + sred[1][lane][29 + n];
        atomicAdd(&Cend[brb * Nz + n], v);
      }
    }
  }
}

// Scan, 8 e's per block (8 waves): dfin+Bm staged ONCE to LDS per block.
// grid = brb(8) x eg(50) = 400 blocks, 512 threads.
__global__ __launch_bounds__(512) void k_scan3(
    const float* __restrict__ xp_t, const float* __restrict__ dfin_g,
    const float* __restrict__ Bm_t, const float* __restrict__ Cend,
    const float* __restrict__ Alogf, const float* __restrict__ Alogb,
    const float* __restrict__ Dpf, const float* __restrict__ Dpb,
    const float* __restrict__ dtwf, const float* __restrict__ dtwb,
    const float* __restrict__ dtbf, const float* __restrict__ dtbb,
    const float* __restrict__ zbuf, const float* __restrict__ vbuf,
    float* __restrict__ ybuf) {
  int bid = blockIdx.x;
  int eg = bid % 50, brb = bid / 50;
  int br = brb >> 2;
  int tid = threadIdx.x;
  int wave = tid >> 6, lane = tid & 63;
  int e = eg * 8 + wave;

  __shared__ float sdf[DTRz * TSTR];   // 26624 B
  __shared__ float sbm[Nz * TSTR];     // 32768 B

  {
    const float4* src = (const float4*)(dfin_g + (size_t)brb * DTRz * TSTR);
    float4* dst = (float4*)sdf;
    for (int i = tid; i < DTRz * TSTR / 4; i += 512) dst[i] = src[i];
    const float4* src2 = (const float4*)(Bm_t + (size_t)brb * Nz * TSTR);
    float4* dst2 = (float4*)sbm;
    for (int i = tid; i < Nz * TSTR / 4; i += 512) dst2[i] = src2[i];
  }
  __syncthreads();

  const float* A_log = br ? Alogb : Alogf;
  const float* Dp = br ? Dpb : Dpf;
  const float* dtw = br ? dtwb : dtwf;
  const float* dtb = br ? dtbb : dtbf;
  float A[Nz];
  {
    const float4* ap = (const float4*)(A_log + e * Nz);
#pragma unroll
    for (int q = 0; q < 4; ++q) {
      float4 a4 = ap[q];
      A[q * 4 + 0] = -__expf(a4.x); A[q * 4 + 1] = -__expf(a4.y);
      A[q * 4 + 2] = -__expf(a4.z); A[q * 4 + 3] = -__expf(a4.w);
    }
  }
  float wq[DTRz];
#pragma unroll
  for (int q = 0; q < DTRz; ++q) wq[q] = dtw[q * EDz + e];
  float dtbe = dtb[e];
  const float* xpp = xp_t + ((size_t)brb * EDz + e) * TSTR;

  float dtt_r[8];
  float loc = 0.f;
#pragma unroll
  for (int c = 0; c < 8; ++c) {
    int t = c * 64 + lane;
    float s = dtbe;
#pragma unroll
    for (int q = 0; q < DTRz; ++q) s += sdf[q * TSTR + t] * wq[q];
    float dtv = (s > 20.f) ? s : log1pf(__expf(s));
    dtv = (t < LPz) ? dtv : 0.f;
    dtt_r[c] = dtv;
    loc += dtv;
  }
  float Stot = wave_sum(loc);
  float acc[Nz];
#pragma unroll
  for (int n = 0; n < Nz; ++n) acc[n] = 0.f;
  float carry = 0.f;
  for (int c = 0; c < 8; ++c) {
    int t = c * 64 + lane;
    bool act = t < LPz;
    float dtt = dtt_r[c];
    float xv = act ? xpp[t] : 0.f;
    float s = dtt;
#pragma unroll
    for (int o = 1; o < 64; o <<= 1) {
      float u = __shfl_up(s, o);
      s += (lane >= o) ? u : 0.f;
    }
    float S = carry + s;
    carry += __shfl(s, 63);
    float wt = dtt * xv;
    float decay = Stot - S;  // >= 0, A<0 => exp<=1
#pragma unroll
    for (int n = 0; n < Nz; ++n) {
      float bv = act ? sbm[n * TSTR + t] : 0.f;
      acc[n] += __expf(A[n] * decay) * wt * bv;
    }
  }
#pragma unroll
  for (int o = 32; o; o >>= 1) {
#pragma unroll
    for (int n = 0; n < Nz; ++n) acc[n] += __shfl_xor(acc[n], o);
  }
  if (lane == 0) {
    float y = Dp[e] * xpp[LPz - 1];
#pragma unroll
    for (int n = 0; n < Nz; ++n) y += Cend[brb * Nz + n] * acc[n];
    float zz = zbuf[(size_t)brb * EDz + e];
    float sz = zz / (1.f + __expf(-zz));
    ybuf[(size_t)brb * EDz + e] = y * sz * vbuf[e];
  }
}

__global__ __launch_bounds__(256) void k_final(
    const float* __restrict__ cls, const float* __restrict__ head_w,
    const float* __restrict__ head_b, const float* __restrict__ ybuf,
    float* __restrict__ out) {
  int tid = threadIdx.x;
  int b = tid >> 6, lane = tid & 63;
  float acc = 0.f;
  for (int e = lane; e < EDz; e += 64)
    acc += ybuf[(size_t)b * EDz + e] + ybuf[(size_t)(Bz + b) * EDz + e];
  for (int d = lane; d < Dz; d += 64) acc += cls[d] * head_w[d];
  acc = wave_sum(acc);
  if (lane == 0) out[b] = 1.f / (1.f + __expf(-(acc + head_b[0])));
}

extern "C" void kernel_launch(void* const* d_in, const int* in_sizes, int n_in,
                              void* d_out, int out_size, void* d_ws, size_t ws_size,
                              hipStream_t stream) {
  const float* input_ids = (const float*)d_in[0];
  const int* n_tweets = (const int*)d_in[1];
  const int* n_words = (const int*)d_in[2];
  const float* cls = (const float*)d_in[3];
  const float* w_attn = (const float*)d_in[4];
  const float* b_attn = (const float*)d_in[5];
  const float* norm_w = (const float*)d_in[6];
  const float* ip[2] = {(const float*)d_in[7], (const float*)d_in[15]};
  const float* cw[2] = {(const float*)d_in[8], (const float*)d_in[16]};
  const float* cb[2] = {(const float*)d_in[9], (const float*)d_in[17]};
  const float* xpj[2] = {(const float*)d_in[10], (const float*)d_in[18]};
  const float* dtw[2] = {(const float*)d_in[11], (const float*)d_in[19]};
  const float* dtbp[2] = {(const float*)d_in[12], (const float*)d_in[20]};
  const float* Alog[2] = {(const float*)d_in[13], (const float*)d_in[21]};
  const float* Dpp[2] = {(const float*)d_in[14], (const float*)d_in[22]};
  const float* out_proj = (const float*)d_in[23];
  const float* head_w = (const float*)d_in[24];
  const float* head_b = (const float*)d_in[25];
  float* out = (float*)d_out;

  float* ws = (float*)d_ws;
  float* xn = ws;                           // 800800
  float* xp_t = xn + 800800;                // 1638400
  float* dfin = xp_t + 1638400;             // 53248   } contiguous zero range
  float* Bm_t = dfin + 53248;               // 65536   }
  float* Cend = Bm_t + 65536;               // 128     } (118912)
  float* zbuf = Cend + 128;                 // 3200
  float* vbuf = zbuf + 3200;                // 400
  float* ybuf = vbuf + 400;                 // 3200

  hipLaunchKernelGGL(k_front, dim3(9 + NZB + Bz * Tz / 4), dim3(256), 0, stream,
                     input_ids, n_tweets, n_words, w_attn, b_attn, norm_w,
                     cls, out_proj, head_w, ip[0], ip[1], xn, zbuf, vbuf, dfin);
  hipLaunchKernelGGL(k_gemmid, dim3(2 * Bz * 8 * NEE), dim3(256), 0, stream,
                     xn, ip[0], ip[1], cw[0], cw[1], cb[0], cb[1],
                     xpj[0], xpj[1], xp_t, dfin, Bm_t, Cend);
  hipLaunchKernelGGL(k_scan3, dim3(2 * Bz * 50), dim3(512), 0, stream,
                     xp_t, dfin, Bm_t, Cend, Alog[0], Alog[1], Dpp[0], Dpp[1],
                     dtw[0], dtw[1], dtbp[0], dtbp[1], zbuf, vbuf, ybuf);
  hipLaunchKernelGGL(k_final, dim3(1), dim3(256), 0, stream,
                     cls, head_w, head_b, ybuf, out);
}